// Round 3
// baseline (564.586 us; speedup 1.0000x reference)
//
#include <hip/hip_runtime.h>
#include <hip/hip_bf16.h>
#include <cstdint>
#include <cstddef>

#define IN_DIM 4096
#define OUT_DIM 4096
#define NTOK 8192
#define PLANE (IN_DIM * OUT_DIM)
#define NPACK_BLOCKS 4096

#define BM 256
#define BN 256
#define BK 64
#define KTILES (IN_DIM / BK)   // 64

typedef int i32x4_t __attribute__((ext_vector_type(4)));

__device__ inline void async_load16(void* lds, const void* g) {
    __builtin_amdgcn_global_load_lds(
        (const __attribute__((address_space(1))) char*)g,
        (__attribute__((address_space(3))) char*)lds,
        16, 0, 0);
}

// Pass 1: decode bit planes -> signed integer code s*k in [-7,7] (EXACT in i8),
// write W^T as i8 via LDS transpose, emit per-block partial sums for the std.
__global__ __launch_bounds__(256) void pack_kernel(const float* __restrict__ mag,
                                                   const float* __restrict__ sgn,
                                                   signed char* __restrict__ wT,
                                                   int* __restrict__ partials) {
    __shared__ short tile[64 * 68];   // [i_local][o_local], stride 68 keeps 8B-aligned rows
    __shared__ int red2[4], reds[4];
    const int t = threadIdx.x;
    const int o0 = blockIdx.x * 64, i0 = blockIdx.y * 64;
    const int oq = t & 15, ir = t >> 4;
    int lk2 = 0, lsk = 0;
    #pragma unroll
    for (int r = 0; r < 4; ++r) {
        const int ilo = r * 16 + ir;
        const size_t idx = (size_t)(i0 + ilo) * OUT_DIM + o0 + oq * 4;
        const float4 m0 = *(const float4*)(mag + idx);
        const float4 m1 = *(const float4*)(mag + idx + (size_t)PLANE);
        const float4 m2 = *(const float4*)(mag + idx + 2 * (size_t)PLANE);
        const float4 sv = *(const float4*)(sgn + idx);
        short4 c;
        {
            int k = ((m0.x >= 0.f) ? 4 : 0) | ((m1.x >= 0.f) ? 2 : 0) | ((m2.x >= 0.f) ? 1 : 0);
            int cd = (sv.x >= 0.f) ? k : -k; lk2 += k * k; lsk += cd; c.x = (short)cd;
        }
        {
            int k = ((m0.y >= 0.f) ? 4 : 0) | ((m1.y >= 0.f) ? 2 : 0) | ((m2.y >= 0.f) ? 1 : 0);
            int cd = (sv.y >= 0.f) ? k : -k; lk2 += k * k; lsk += cd; c.y = (short)cd;
        }
        {
            int k = ((m0.z >= 0.f) ? 4 : 0) | ((m1.z >= 0.f) ? 2 : 0) | ((m2.z >= 0.f) ? 1 : 0);
            int cd = (sv.z >= 0.f) ? k : -k; lk2 += k * k; lsk += cd; c.z = (short)cd;
        }
        {
            int k = ((m0.w >= 0.f) ? 4 : 0) | ((m1.w >= 0.f) ? 2 : 0) | ((m2.w >= 0.f) ? 1 : 0);
            int cd = (sv.w >= 0.f) ? k : -k; lk2 += k * k; lsk += cd; c.w = (short)cd;
        }
        *(short4*)&tile[ilo * 68 + oq * 4] = c;
    }
    #pragma unroll
    for (int off = 32; off > 0; off >>= 1) {
        lk2 += __shfl_down(lk2, off);
        lsk += __shfl_down(lsk, off);
    }
    const int wv = t >> 6, ln = t & 63;
    if (ln == 0) { red2[wv] = lk2; reds[wv] = lsk; }
    __syncthreads();
    if (t == 0) {
        const int bid = blockIdx.y * gridDim.x + blockIdx.x;
        partials[bid] = red2[0] + red2[1] + red2[2] + red2[3];
        partials[NPACK_BLOCKS + bid] = reds[0] + reds[1] + reds[2] + reds[3];
    }
    // transposed write: wT[o][i] as i8, char4 along i
    const int iq = t & 15, orr = t >> 4;
    #pragma unroll
    for (int r = 0; r < 4; ++r) {
        const int olo = r * 16 + orr;
        char4 w4;
        w4.x = (signed char)tile[(iq * 4 + 0) * 68 + olo];
        w4.y = (signed char)tile[(iq * 4 + 1) * 68 + olo];
        w4.z = (signed char)tile[(iq * 4 + 2) * 68 + olo];
        w4.w = (signed char)tile[(iq * 4 + 3) * 68 + olo];
        *(char4*)&wT[(size_t)(o0 + olo) * IN_DIM + i0 + iq * 4] = w4;
    }
}

// Reduce partial pairs -> alpha/8 (the /8 folds the k/8 magnitude scaling).
__global__ __launch_bounds__(256) void alpha_kernel(const int* __restrict__ partials,
                                                    float* __restrict__ alpha8) {
    __shared__ int red2[4], reds[4];
    const int t = threadIdx.x;
    int k2 = 0, sk = 0;
    for (int i = t; i < NPACK_BLOCKS; i += 256) {
        k2 += partials[i];
        sk += partials[NPACK_BLOCKS + i];
    }
    #pragma unroll
    for (int off = 32; off > 0; off >>= 1) {
        k2 += __shfl_down(k2, off);
        sk += __shfl_down(sk, off);
    }
    const int wv = t >> 6, ln = t & 63;
    if (ln == 0) { red2[wv] = k2; reds[wv] = sk; }
    __syncthreads();
    if (t == 0) {
        const double n = (double)PLANE;
        const double sumk2 = (double)(red2[0] + red2[1] + red2[2] + red2[3]);
        const double sumsk = (double)(reds[0] + reds[1] + reds[2] + reds[3]);
        const double mean = sumsk / (8.0 * n);
        const double e2 = sumk2 / (64.0 * n);
        const double sd = sqrt(e2 - mean * mean);
        *alpha8 = (float)(sqrt(2.0 / (double)IN_DIM) / (sd + 1e-12) * 0.125);
    }
}

// Per-token-row symmetric i8 quantization of x. One block per row.
__global__ __launch_bounds__(256) void quant_kernel(const float* __restrict__ x,
                                                    signed char* __restrict__ xq,
                                                    float* __restrict__ steps) {
    __shared__ float red[4];
    const int r = blockIdx.x, t = threadIdx.x;
    const float* xr = x + (size_t)r * IN_DIM;
    float4 v[4];
    float am = 0.f;
    #pragma unroll
    for (int p = 0; p < 4; ++p) {
        v[p] = ((const float4*)xr)[p * 256 + t];
        am = fmaxf(am, fmaxf(fmaxf(fabsf(v[p].x), fabsf(v[p].y)),
                             fmaxf(fabsf(v[p].z), fabsf(v[p].w))));
    }
    #pragma unroll
    for (int off = 32; off > 0; off >>= 1) am = fmaxf(am, __shfl_down(am, off));
    const int wv = t >> 6, ln = t & 63;
    if (ln == 0) red[wv] = am;
    __syncthreads();
    am = fmaxf(fmaxf(red[0], red[1]), fmaxf(red[2], red[3]));
    am = fmaxf(am, 1e-30f);
    const float rstep = 127.0f / am;
    if (t == 0) steps[r] = am * (1.0f / 127.0f);
    int* xqi = (int*)(xq + (size_t)r * IN_DIM);
    #pragma unroll
    for (int p = 0; p < 4; ++p) {
        const int q0 = (int)rintf(v[p].x * rstep);
        const int q1 = (int)rintf(v[p].y * rstep);
        const int q2 = (int)rintf(v[p].z * rstep);
        const int q3 = (int)rintf(v[p].w * rstep);
        xqi[p * 256 + t] = (q0 & 0xFF) | ((q1 & 0xFF) << 8) | ((q2 & 0xFF) << 16) | (q3 << 24);
    }
}

// i8 GEMM, 256x256 tile, BK=64, 8 waves (2Mx4N), 4-deep LDS pipeline with
// counted vmcnt (3 tiles / 12 loads in flight across raw s_barriers — T3/T4),
// XOR-swizzled LDS (pre-swizzled global source + swizzled ds_read — T2),
// setprio around each MFMA cluster (T5), bijective XCD block swizzle (T1).
// R2 (infra-flake retry): per-K-tile compute split into 4 phases {ds_read
// subtile; barrier; 8 MFMA; barrier} so the LDS pipe (other waves' phase-p
// reads) overlaps the matrix pipe (this wave's phase-p MFMAs) instead of
// alternating in CU-wide bursts.  mfma_i32_16x16x64_i8, exact i32 accum;
// epilogue scales by alpha/8 * per-row step. |acc| < 2^22 -> exact f32 cvt.
__global__ __launch_bounds__(512, 2) void gemm_kernel(const signed char* __restrict__ A,
                                                      const signed char* __restrict__ B,
                                                      float* __restrict__ C,
                                                      const float* __restrict__ alphap,
                                                      const float* __restrict__ steps) {
    __shared__ __align__(16) signed char As[4][BM * BK];   // 4 x 16 KB
    __shared__ __align__(16) signed char Bs[4][BN * BK];   // 4 x 16 KB
    const int t = threadIdx.x;
    const int lane = t & 63;
    const int wave = t >> 6;               // 8 waves
    const int wm = wave >> 2, wn = wave & 3;   // 2 x 4 -> per-wave 128x64 of C
    const int r15 = lane & 15, q = lane >> 4;

    // T1: XCD-contiguous block swizzle (512 wgs, 512 % 8 == 0 -> bijective)
    const int raw = blockIdx.x;
    const int wg = (raw & 7) * 64 + (raw >> 3);
    const int m0 = (wg >> 4) * BM;         // 32 m-blocks
    const int n0 = (wg & 15) * BN;         // 16 n-blocks (fastest within an XCD)

    // T2 swizzled ds_read byte offsets: chunk q -> q ^ ((row>>1)&3).
    // Lanes 0-15 (rows r..r+15, fixed q) then hit 8 distinct bank-groups
    // (2-way aliasing only, which is free).
    int aoff[8], boff[4];
    #pragma unroll
    for (int i = 0; i < 8; ++i) {
        const int r = wm * 128 + i * 16 + r15;
        aoff[i] = r * BK + ((q ^ ((r >> 1) & 3)) << 4);
    }
    #pragma unroll
    for (int i = 0; i < 4; ++i) {
        const int r = wn * 64 + i * 16 + r15;
        boff[i] = r * BK + ((q ^ ((r >> 1) & 3)) << 4);
    }

    // Staging: LDS written LINEARLY by global_load_lds (base + lane*16);
    // the inverse swizzle is applied to the GLOBAL source column (rule #21).
    // 1024 16B chunks per 16KB tile, 512 threads -> 2 chunks each.
    const int c0 = t, c1 = t + 512;
    const int ra0 = c0 >> 2, ra1 = c1 >> 2;                  // row in tile
    const int sc0 = (((c0 & 3) ^ ((c0 >> 3) & 3)) << 4);     // swizzled src col
    const int sc1 = (((c1 & 3) ^ ((c1 >> 3) & 3)) << 4);
    const size_t srcA0 = (size_t)(m0 + ra0) * IN_DIM + sc0;
    const size_t srcA1 = (size_t)(m0 + ra1) * IN_DIM + sc1;
    const size_t srcB0 = (size_t)(n0 + ra0) * IN_DIM + sc0;
    const size_t srcB1 = (size_t)(n0 + ra1) * IN_DIM + sc1;

    i32x4_t acc[8][4] = {};
    i32x4_t b_[4];

#define STAGE(kt, buf) do {                                          \
        const int koff_ = (kt) * BK;                                 \
        async_load16(&As[buf][c0 * 16], A + srcA0 + koff_);          \
        async_load16(&As[buf][c1 * 16], A + srcA1 + koff_);          \
        async_load16(&Bs[buf][c0 * 16], B + srcB0 + koff_);          \
        async_load16(&Bs[buf][c1 * 16], B + srcB1 + koff_);          \
    } while (0)

    // One phase: read this phase's A-frag pair (+ all B frags in phase 0),
    // sync, run the 8-MFMA cluster under setprio, sync.  p is a literal.
#define PHASE(buf, p) do {                                           \
        const i32x4_t a0_ = *(const i32x4_t*)&As[buf][aoff[2*(p)]];  \
        const i32x4_t a1_ = *(const i32x4_t*)&As[buf][aoff[2*(p)+1]];\
        if ((p) == 0) {                                              \
            b_[0] = *(const i32x4_t*)&Bs[buf][boff[0]];              \
            b_[1] = *(const i32x4_t*)&Bs[buf][boff[1]];              \
            b_[2] = *(const i32x4_t*)&Bs[buf][boff[2]];              \
            b_[3] = *(const i32x4_t*)&Bs[buf][boff[3]];              \
        }                                                            \
        __builtin_amdgcn_s_barrier();                                \
        __builtin_amdgcn_s_setprio(1);                               \
        _Pragma("unroll")                                            \
        for (int nt = 0; nt < 4; ++nt)                               \
            acc[2*(p)][nt] = __builtin_amdgcn_mfma_i32_16x16x64_i8(  \
                a0_, b_[nt], acc[2*(p)][nt], 0, 0, 0);               \
        _Pragma("unroll")                                            \
        for (int nt = 0; nt < 4; ++nt)                               \
            acc[2*(p)+1][nt] = __builtin_amdgcn_mfma_i32_16x16x64_i8(\
                a1_, b_[nt], acc[2*(p)+1][nt], 0, 0, 0);             \
        __builtin_amdgcn_s_setprio(0);                               \
        __builtin_amdgcn_s_barrier();                                \
    } while (0)

#define COMPUTE4(buf) do {                                           \
        PHASE(buf, 0); PHASE(buf, 1); PHASE(buf, 2); PHASE(buf, 3);  \
    } while (0)

    // Prologue: 3 tiles in flight before first compute.
    STAGE(0, 0); STAGE(1, 1); STAGE(2, 2);

    // Main loop: issue tile kt+3 (its buffer's last reads finished at kt-1's
    // trailing phase barrier), then wait until tile kt has landed — 12 loads
    // (tiles kt+1..kt+3) stay in flight across all the phase barriers.
    #pragma unroll 4
    for (int kt = 0; kt < KTILES - 3; ++kt) {
        STAGE(kt + 3, (kt + 3) & 3);
        asm volatile("s_waitcnt vmcnt(12)" ::: "memory");
        __builtin_amdgcn_s_barrier();        // all waves' tile-kt loads landed
        COMPUTE4(kt & 3);
    }
    // Tail: drain 12 -> 8 -> 4 -> 0.
    asm volatile("s_waitcnt vmcnt(8)" ::: "memory");
    __builtin_amdgcn_s_barrier();
    COMPUTE4((KTILES - 3) & 3);
    asm volatile("s_waitcnt vmcnt(4)" ::: "memory");
    __builtin_amdgcn_s_barrier();
    COMPUTE4((KTILES - 2) & 3);
    asm volatile("s_waitcnt vmcnt(0)" ::: "memory");
    __builtin_amdgcn_s_barrier();
    COMPUTE4((KTILES - 1) & 3);

#undef COMPUTE4
#undef PHASE
#undef STAGE

    const float alpha8 = *alphap;
    #pragma unroll
    for (int mt = 0; mt < 8; ++mt) {
        const int mbase = m0 + wm * 128 + mt * 16 + q * 4;
        const float s0 = alpha8 * steps[mbase + 0];
        const float s1 = alpha8 * steps[mbase + 1];
        const float s2 = alpha8 * steps[mbase + 2];
        const float s3 = alpha8 * steps[mbase + 3];
        #pragma unroll
        for (int nt = 0; nt < 4; ++nt) {
            const int n = n0 + wn * 64 + nt * 16 + r15;
            float* cp = C + (size_t)mbase * OUT_DIM + n;
            cp[0 * OUT_DIM] = (float)acc[mt][nt][0] * s0;
            cp[1 * OUT_DIM] = (float)acc[mt][nt][1] * s1;
            cp[2 * OUT_DIM] = (float)acc[mt][nt][2] * s2;
            cp[3 * OUT_DIM] = (float)acc[mt][nt][3] * s3;
        }
    }
}

extern "C" void kernel_launch(void* const* d_in, const int* in_sizes, int n_in,
                              void* d_out, int out_size, void* d_ws, size_t ws_size,
                              hipStream_t stream) {
    const float* x   = (const float*)d_in[0];
    const float* mag = (const float*)d_in[1];
    const float* sgn = (const float*)d_in[2];
    float* out = (float*)d_out;

    char* ws = (char*)d_ws;
    int* partials = (int*)ws;                                  // 32 KB
    float* alphap = (float*)(ws + 32768);
    float* steps  = (float*)(ws + 65536);                      // 8192 floats
    signed char* wT = (signed char*)(ws + 131072);             // [OUT][IN] i8, 16.7 MB
    signed char* xq = (signed char*)(ws + 131072 + (size_t)PLANE);  // [NTOK][IN] i8, 33.5 MB

    pack_kernel<<<dim3(OUT_DIM / 64, IN_DIM / 64), 256, 0, stream>>>(mag, sgn, wT, partials);
    quant_kernel<<<NTOK, 256, 0, stream>>>(x, xq, steps);
    alpha_kernel<<<1, 256, 0, stream>>>(partials, alphap);
    gemm_kernel<<<dim3((NTOK / BM) * (OUT_DIM / BN)), 512, 0, stream>>>(xq, wT, out, alphap, steps);
}

// Round 4
// 551.634 us; speedup vs baseline: 1.0235x; 1.0235x over previous
//
#include <hip/hip_runtime.h>
#include <hip/hip_bf16.h>
#include <cstdint>
#include <cstddef>

#define IN_DIM 4096
#define OUT_DIM 4096
#define NTOK 8192
#define PLANE (IN_DIM * OUT_DIM)
#define NPACK_BLOCKS 4096

#define BM 256
#define BN 256
#define BK 64
#define KTILES (IN_DIM / BK)   // 64

typedef int i32x4_t __attribute__((ext_vector_type(4)));

__device__ inline void async_load16(void* lds, const void* g) {
    __builtin_amdgcn_global_load_lds(
        (const __attribute__((address_space(1))) char*)g,
        (__attribute__((address_space(3))) char*)lds,
        16, 0, 0);
}

// Pass 1: decode bit planes -> signed integer code s*k in [-7,7] (EXACT in i8),
// write W^T as i8 via LDS transpose, emit per-block partial sums for the std.
__global__ __launch_bounds__(256) void pack_kernel(const float* __restrict__ mag,
                                                   const float* __restrict__ sgn,
                                                   signed char* __restrict__ wT,
                                                   int* __restrict__ partials) {
    __shared__ short tile[64 * 68];   // [i_local][o_local], stride 68 keeps 8B-aligned rows
    __shared__ int red2[4], reds[4];
    const int t = threadIdx.x;
    const int o0 = blockIdx.x * 64, i0 = blockIdx.y * 64;
    const int oq = t & 15, ir = t >> 4;
    int lk2 = 0, lsk = 0;
    #pragma unroll
    for (int r = 0; r < 4; ++r) {
        const int ilo = r * 16 + ir;
        const size_t idx = (size_t)(i0 + ilo) * OUT_DIM + o0 + oq * 4;
        const float4 m0 = *(const float4*)(mag + idx);
        const float4 m1 = *(const float4*)(mag + idx + (size_t)PLANE);
        const float4 m2 = *(const float4*)(mag + idx + 2 * (size_t)PLANE);
        const float4 sv = *(const float4*)(sgn + idx);
        short4 c;
        {
            int k = ((m0.x >= 0.f) ? 4 : 0) | ((m1.x >= 0.f) ? 2 : 0) | ((m2.x >= 0.f) ? 1 : 0);
            int cd = (sv.x >= 0.f) ? k : -k; lk2 += k * k; lsk += cd; c.x = (short)cd;
        }
        {
            int k = ((m0.y >= 0.f) ? 4 : 0) | ((m1.y >= 0.f) ? 2 : 0) | ((m2.y >= 0.f) ? 1 : 0);
            int cd = (sv.y >= 0.f) ? k : -k; lk2 += k * k; lsk += cd; c.y = (short)cd;
        }
        {
            int k = ((m0.z >= 0.f) ? 4 : 0) | ((m1.z >= 0.f) ? 2 : 0) | ((m2.z >= 0.f) ? 1 : 0);
            int cd = (sv.z >= 0.f) ? k : -k; lk2 += k * k; lsk += cd; c.z = (short)cd;
        }
        {
            int k = ((m0.w >= 0.f) ? 4 : 0) | ((m1.w >= 0.f) ? 2 : 0) | ((m2.w >= 0.f) ? 1 : 0);
            int cd = (sv.w >= 0.f) ? k : -k; lk2 += k * k; lsk += cd; c.w = (short)cd;
        }
        *(short4*)&tile[ilo * 68 + oq * 4] = c;
    }
    #pragma unroll
    for (int off = 32; off > 0; off >>= 1) {
        lk2 += __shfl_down(lk2, off);
        lsk += __shfl_down(lsk, off);
    }
    const int wv = t >> 6, ln = t & 63;
    if (ln == 0) { red2[wv] = lk2; reds[wv] = lsk; }
    __syncthreads();
    if (t == 0) {
        const int bid = blockIdx.y * gridDim.x + blockIdx.x;
        partials[bid] = red2[0] + red2[1] + red2[2] + red2[3];
        partials[NPACK_BLOCKS + bid] = reds[0] + reds[1] + reds[2] + reds[3];
    }
    // transposed write: wT[o][i] as i8, char4 along i
    const int iq = t & 15, orr = t >> 4;
    #pragma unroll
    for (int r = 0; r < 4; ++r) {
        const int olo = r * 16 + orr;
        char4 w4;
        w4.x = (signed char)tile[(iq * 4 + 0) * 68 + olo];
        w4.y = (signed char)tile[(iq * 4 + 1) * 68 + olo];
        w4.z = (signed char)tile[(iq * 4 + 2) * 68 + olo];
        w4.w = (signed char)tile[(iq * 4 + 3) * 68 + olo];
        *(char4*)&wT[(size_t)(o0 + olo) * IN_DIM + i0 + iq * 4] = w4;
    }
}

// Reduce partial pairs -> alpha/8 (the /8 folds the k/8 magnitude scaling).
__global__ __launch_bounds__(256) void alpha_kernel(const int* __restrict__ partials,
                                                    float* __restrict__ alpha8) {
    __shared__ int red2[4], reds[4];
    const int t = threadIdx.x;
    int k2 = 0, sk = 0;
    for (int i = t; i < NPACK_BLOCKS; i += 256) {
        k2 += partials[i];
        sk += partials[NPACK_BLOCKS + i];
    }
    #pragma unroll
    for (int off = 32; off > 0; off >>= 1) {
        k2 += __shfl_down(k2, off);
        sk += __shfl_down(sk, off);
    }
    const int wv = t >> 6, ln = t & 63;
    if (ln == 0) { red2[wv] = k2; reds[wv] = sk; }
    __syncthreads();
    if (t == 0) {
        const double n = (double)PLANE;
        const double sumk2 = (double)(red2[0] + red2[1] + red2[2] + red2[3]);
        const double sumsk = (double)(reds[0] + reds[1] + reds[2] + reds[3]);
        const double mean = sumsk / (8.0 * n);
        const double e2 = sumk2 / (64.0 * n);
        const double sd = sqrt(e2 - mean * mean);
        *alpha8 = (float)(sqrt(2.0 / (double)IN_DIM) / (sd + 1e-12) * 0.125);
    }
}

// Per-token-row symmetric i8 quantization of x. One block per row.
__global__ __launch_bounds__(256) void quant_kernel(const float* __restrict__ x,
                                                    signed char* __restrict__ xq,
                                                    float* __restrict__ steps) {
    __shared__ float red[4];
    const int r = blockIdx.x, t = threadIdx.x;
    const float* xr = x + (size_t)r * IN_DIM;
    float4 v[4];
    float am = 0.f;
    #pragma unroll
    for (int p = 0; p < 4; ++p) {
        v[p] = ((const float4*)xr)[p * 256 + t];
        am = fmaxf(am, fmaxf(fmaxf(fabsf(v[p].x), fabsf(v[p].y)),
                             fmaxf(fabsf(v[p].z), fabsf(v[p].w))));
    }
    #pragma unroll
    for (int off = 32; off > 0; off >>= 1) am = fmaxf(am, __shfl_down(am, off));
    const int wv = t >> 6, ln = t & 63;
    if (ln == 0) red[wv] = am;
    __syncthreads();
    am = fmaxf(fmaxf(red[0], red[1]), fmaxf(red[2], red[3]));
    am = fmaxf(am, 1e-30f);
    const float rstep = 127.0f / am;
    if (t == 0) steps[r] = am * (1.0f / 127.0f);
    int* xqi = (int*)(xq + (size_t)r * IN_DIM);
    #pragma unroll
    for (int p = 0; p < 4; ++p) {
        const int q0 = (int)rintf(v[p].x * rstep);
        const int q1 = (int)rintf(v[p].y * rstep);
        const int q2 = (int)rintf(v[p].z * rstep);
        const int q3 = (int)rintf(v[p].w * rstep);
        xqi[p * 256 + t] = (q0 & 0xFF) | ((q1 & 0xFF) << 8) | ((q2 & 0xFF) << 16) | (q3 << 24);
    }
}

// i8 GEMM, 256x256 tile, BK=64. R4: 1024 threads / 16 waves in a 4x4 wave
// grid (per-wave 64x64 output, acc[4][4] = 64 acc regs) -> 4 waves/SIMD for
// wave-level TLP: while some waves sit in lgkm/vmcnt waits, others feed the
// matrix pipe (m114 co-scheduling). Monolithic per-tile compute (R3's
// per-phase barriers regressed -> reverted). 4-deep LDS pipeline with
// counted vmcnt (3 tiles in flight across barriers — T3/T4), XOR-swizzled
// LDS (pre-swizzled global source + swizzled ds_read — T2), setprio around
// the MFMA cluster (T5), bijective XCD block swizzle (T1).
// mfma_i32_16x16x64_i8, exact i32 accum; epilogue scales by alpha/8 *
// per-row step.  |acc| <= 127*7*4096 < 2^22 -> exact f32 cvt.
__global__ __launch_bounds__(1024, 4) void gemm_kernel(const signed char* __restrict__ A,
                                                       const signed char* __restrict__ B,
                                                       float* __restrict__ C,
                                                       const float* __restrict__ alphap,
                                                       const float* __restrict__ steps) {
    __shared__ __align__(16) signed char As[4][BM * BK];   // 4 x 16 KB
    __shared__ __align__(16) signed char Bs[4][BN * BK];   // 4 x 16 KB
    const int t = threadIdx.x;
    const int lane = t & 63;
    const int wave = t >> 6;                   // 16 waves
    const int wm = wave >> 2, wn = wave & 3;   // 4 x 4 -> per-wave 64x64 of C
    const int r15 = lane & 15, q = lane >> 4;

    // T1: XCD-contiguous block swizzle (512 wgs, 512 % 8 == 0 -> bijective)
    const int raw = blockIdx.x;
    const int wg = (raw & 7) * 64 + (raw >> 3);
    const int m0 = (wg >> 4) * BM;         // 32 m-blocks
    const int n0 = (wg & 15) * BN;         // 16 n-blocks (fastest within an XCD)

    // T2 swizzled ds_read byte offsets: chunk q -> q ^ ((row>>1)&3).
    // Lanes 0-15 (rows r..r+15, fixed q) spread over 8 distinct bank-groups
    // (2-way aliasing only, which is free; R1 measured 0 conflicts).
    int aoff[4], boff[4];
    #pragma unroll
    for (int i = 0; i < 4; ++i) {
        const int r = wm * 64 + i * 16 + r15;
        aoff[i] = r * BK + ((q ^ ((r >> 1) & 3)) << 4);
    }
    #pragma unroll
    for (int i = 0; i < 4; ++i) {
        const int r = wn * 64 + i * 16 + r15;
        boff[i] = r * BK + ((q ^ ((r >> 1) & 3)) << 4);
    }

    // Staging: LDS written LINEARLY by global_load_lds (base + lane*16);
    // the inverse swizzle is applied to the GLOBAL source column (rule #21).
    // 1024 16B chunks per 16KB tile, 1024 threads -> 1 A-chunk + 1 B-chunk
    // per thread per tile.
    const int ra = t >> 2;                               // row in tile (0..255)
    const int sc = (((t & 3) ^ ((t >> 3) & 3)) << 4);    // swizzled src col
    const size_t srcA = (size_t)(m0 + ra) * IN_DIM + sc;
    const size_t srcB = (size_t)(n0 + ra) * IN_DIM + sc;

    i32x4_t acc[4][4] = {};

#define STAGE(kt, buf) do {                                          \
        const int koff_ = (kt) * BK;                                 \
        async_load16(&As[buf][t * 16], A + srcA + koff_);            \
        async_load16(&Bs[buf][t * 16], B + srcB + koff_);            \
    } while (0)

#define COMPUTE(buf) do {                                            \
        i32x4_t a_[4], b_[4];                                        \
        _Pragma("unroll")                                            \
        for (int i = 0; i < 4; ++i)                                  \
            a_[i] = *(const i32x4_t*)&As[buf][aoff[i]];              \
        _Pragma("unroll")                                            \
        for (int i = 0; i < 4; ++i)                                  \
            b_[i] = *(const i32x4_t*)&Bs[buf][boff[i]];              \
        __builtin_amdgcn_s_setprio(1);                               \
        _Pragma("unroll")                                            \
        for (int mt = 0; mt < 4; ++mt)                               \
            _Pragma("unroll")                                        \
            for (int nt = 0; nt < 4; ++nt)                           \
                acc[mt][nt] = __builtin_amdgcn_mfma_i32_16x16x64_i8( \
                    a_[mt], b_[nt], acc[mt][nt], 0, 0, 0);           \
        __builtin_amdgcn_s_setprio(0);                               \
    } while (0)

    // Prologue: 3 tiles in flight (6 loads/wave-lane) before first compute.
    STAGE(0, 0); STAGE(1, 1); STAGE(2, 2);

    // Main loop: issue tile kt+3 (its buffer's last reads finished at kt-1's
    // trailing barrier), then wait until tile kt has landed — 6 outstanding
    // loads (tiles kt+1..kt+3) stay in flight across the barriers.
    #pragma unroll 4
    for (int kt = 0; kt < KTILES - 3; ++kt) {
        STAGE(kt + 3, (kt + 3) & 3);
        asm volatile("s_waitcnt vmcnt(6)" ::: "memory");
        __builtin_amdgcn_s_barrier();        // all waves' tile-kt loads landed
        COMPUTE(kt & 3);
        __builtin_amdgcn_s_barrier();        // reads done before buf is restaged
    }
    // Tail: drain 6 -> 4 -> 2 -> 0.
    asm volatile("s_waitcnt vmcnt(4)" ::: "memory");
    __builtin_amdgcn_s_barrier();
    COMPUTE((KTILES - 3) & 3);
    __builtin_amdgcn_s_barrier();
    asm volatile("s_waitcnt vmcnt(2)" ::: "memory");
    __builtin_amdgcn_s_barrier();
    COMPUTE((KTILES - 2) & 3);
    __builtin_amdgcn_s_barrier();
    asm volatile("s_waitcnt vmcnt(0)" ::: "memory");
    __builtin_amdgcn_s_barrier();
    COMPUTE((KTILES - 1) & 3);

#undef COMPUTE
#undef STAGE

    const float alpha8 = *alphap;
    #pragma unroll
    for (int mt = 0; mt < 4; ++mt) {
        const int mbase = m0 + wm * 64 + mt * 16 + q * 4;
        const float s0 = alpha8 * steps[mbase + 0];
        const float s1 = alpha8 * steps[mbase + 1];
        const float s2 = alpha8 * steps[mbase + 2];
        const float s3 = alpha8 * steps[mbase + 3];
        #pragma unroll
        for (int nt = 0; nt < 4; ++nt) {
            const int n = n0 + wn * 64 + nt * 16 + r15;
            float* cp = C + (size_t)mbase * OUT_DIM + n;
            cp[0 * OUT_DIM] = (float)acc[mt][nt][0] * s0;
            cp[1 * OUT_DIM] = (float)acc[mt][nt][1] * s1;
            cp[2 * OUT_DIM] = (float)acc[mt][nt][2] * s2;
            cp[3 * OUT_DIM] = (float)acc[mt][nt][3] * s3;
        }
    }
}

extern "C" void kernel_launch(void* const* d_in, const int* in_sizes, int n_in,
                              void* d_out, int out_size, void* d_ws, size_t ws_size,
                              hipStream_t stream) {
    const float* x   = (const float*)d_in[0];
    const float* mag = (const float*)d_in[1];
    const float* sgn = (const float*)d_in[2];
    float* out = (float*)d_out;

    char* ws = (char*)d_ws;
    int* partials = (int*)ws;                                  // 32 KB
    float* alphap = (float*)(ws + 32768);
    float* steps  = (float*)(ws + 65536);                      // 8192 floats
    signed char* wT = (signed char*)(ws + 131072);             // [OUT][IN] i8, 16.7 MB
    signed char* xq = (signed char*)(ws + 131072 + (size_t)PLANE);  // [NTOK][IN] i8, 33.5 MB

    pack_kernel<<<dim3(OUT_DIM / 64, IN_DIM / 64), 256, 0, stream>>>(mag, sgn, wT, partials);
    quant_kernel<<<NTOK, 256, 0, stream>>>(x, xq, steps);
    alpha_kernel<<<1, 256, 0, stream>>>(partials, alphap);
    gemm_kernel<<<dim3((NTOK / BM) * (OUT_DIM / BN)), 1024, 0, stream>>>(xq, wT, out, alphap, steps);
}